// Round 3
// baseline (124.957 us; speedup 1.0000x reference)
//
#include <hip/hip_runtime.h>

// ACCriticNSMsg — bf16 hi/lo split MFMA version.
// bs=64, T=256, n=8, msg=16, obs=128, hidden=64, in_dim=240. out: (bs,T,n,1) f32.
//
// Per agent a: X_a (16384 x 240) @ W1_a (240 x 64) -> relu(+b1) -> @W2 (+b2).
// X cols 0..127 = obs[:,:,a,:]; cols 128..239 = messages[t-1, j!=a] (ascending j),
// zeros at t==0.
//
// hi/lo split: x = hi(bf16) + lo(bf16 of residual); 3 MFMA passes
// (hi*Whi + lo*Whi + hi*Wlo) ~ fp32 precision. K=240 = 15 steps of
// mfma_f32_32x32x16_bf16 (exact, no padding).
//
// Layout-robustness: W1 fragments are staged in LDS in the SAME per-lane
// (row=l&31 / col=l&31, kgroup=l>>5, 8 regs) convention used to pack A from
// global. Any k-permutation error inside the lane's 8 elements cancels
// between A and B. Only the HW-verified C/D mapping is relied upon:
// col=lane&31, row=(reg&3)+8*(reg>>2)+4*(lane>>5).

#define NAGENTS 8
#define MSG_LEN 16
#define OBS_DIM 128
#define HIDDEN  64
#define IN_DIM  240
#define TT      256
#define ROWS    16384
#define KSTEPS  15
#define MTILE   256
#define NFRAG   (KSTEPS * 2 * 64 * 8)   // 15360 bf16 = one full W1_a

typedef __attribute__((ext_vector_type(8)))  short bf16x8;
typedef __attribute__((ext_vector_type(16))) float f32x16;

__device__ __forceinline__ unsigned short f2bf(float x) {
    unsigned u = __float_as_uint(x);
    u += 0x7fffu + ((u >> 16) & 1u);
    return (unsigned short)(u >> 16);
}
__device__ __forceinline__ float bf2f(unsigned short h) {
    return __uint_as_float(((unsigned)h) << 16);
}

__global__ __launch_bounds__(512, 4) void accritic_mfma_kernel(
    const float* __restrict__ obs,   // (bs,T,n,128)
    const float* __restrict__ msgs,  // (bs,T,n,16)
    const float* __restrict__ W1,    // (n,240,64)
    const float* __restrict__ b1,    // (n,64)
    const float* __restrict__ W2,    // (n,64,1)
    const float* __restrict__ b2,    // (n,1)
    float* __restrict__ out)         // (bs,T,n,1)
{
    __shared__ unsigned short WH[NFRAG];
    __shared__ unsigned short WL[NFRAG];

    const int a   = blockIdx.y;
    const int tid = threadIdx.x;
    const float* __restrict__ w1a = W1 + (size_t)a * IN_DIM * HIDDEN;

    // ---- stage W1_a as hi/lo bf16 fragments, fragment-order ----
    // entry e = ((ks*2 + nt)*64 + lane)*8 + j  ->  k = ks*16 + (lane>>5)*8 + j,
    //                                              col = nt*32 + (lane&31)
#pragma unroll
    for (int i = 0; i < NFRAG / 512; ++i) {       // 30 entries/thread
        int e    = tid + i * 512;
        int j    = e & 7;
        int lane = (e >> 3) & 63;
        int nt   = (e >> 9) & 1;
        int ks   = e >> 10;
        int k    = ks * 16 + (lane >> 5) * 8 + j;     // max 239
        int col  = nt * 32 + (lane & 31);
        float w  = w1a[k * HIDDEN + col];
        unsigned short h = f2bf(w);
        WH[e] = h;
        WL[e] = f2bf(w - bf2f(h));
    }
    __syncthreads();

    const int wv   = tid >> 6;
    const int lane = tid & 63;
    const int rl   = lane & 31;      // A row within 32-row slab
    const int kg   = lane >> 5;      // k-group (8 elems each)
    const int r    = blockIdx.x * MTILE + wv * 32 + rl;   // global row = b*T + t
    const int t    = r & (TT - 1);
    const bool zmsg = (t == 0);
    const int  rs   = zmsg ? r : r - 1;   // safe source row for messages

    const float* __restrict__ obsp = obs + ((size_t)r * NAGENTS + a) * OBS_DIM + kg * 8;
    const float* __restrict__ msgp = msgs + (size_t)rs * NAGENTS * MSG_LEN + kg * 8;

    f32x16 acc0, acc1;
#pragma unroll
    for (int i = 0; i < 16; ++i) { acc0[i] = 0.f; acc1[i] = 0.f; }

    const bf16x8* __restrict__ WH8 = reinterpret_cast<const bf16x8*>(WH);
    const bf16x8* __restrict__ WL8 = reinterpret_cast<const bf16x8*>(WL);

#pragma unroll
    for (int ks = 0; ks < KSTEPS; ++ks) {
        float4 f0, f1;
        if (ks < 8) {                                   // obs: k = ks*16 + kg*8 ..
            const float4* p = reinterpret_cast<const float4*>(obsp + ks * 16);
            f0 = p[0]; f1 = p[1];
        } else {                                        // messages, src agent jsrc
            int pidx = ks - 8;                          // 0..6
            int jsrc = (pidx < a) ? pidx : pidx + 1;    // ascending j != a
            const float4* p = reinterpret_cast<const float4*>(msgp + jsrc * MSG_LEN);
            f0 = p[0]; f1 = p[1];
            if (zmsg) { f0 = make_float4(0.f, 0.f, 0.f, 0.f); f1 = f0; }
        }

        float xf[8] = { f0.x, f0.y, f0.z, f0.w, f1.x, f1.y, f1.z, f1.w };
        bf16x8 ahi, alo;
#pragma unroll
        for (int q = 0; q < 8; ++q) {
            unsigned short h = f2bf(xf[q]);
            ahi[q] = (short)h;
            alo[q] = (short)f2bf(xf[q] - bf2f(h));
        }

        bf16x8 bh0 = WH8[(ks * 2 + 0) * 64 + lane];
        bf16x8 bh1 = WH8[(ks * 2 + 1) * 64 + lane];
        bf16x8 bl0 = WL8[(ks * 2 + 0) * 64 + lane];
        bf16x8 bl1 = WL8[(ks * 2 + 1) * 64 + lane];

        acc0 = __builtin_amdgcn_mfma_f32_32x32x16_bf16(ahi, bh0, acc0, 0, 0, 0);
        acc1 = __builtin_amdgcn_mfma_f32_32x32x16_bf16(ahi, bh1, acc1, 0, 0, 0);
        acc0 = __builtin_amdgcn_mfma_f32_32x32x16_bf16(alo, bh0, acc0, 0, 0, 0);
        acc1 = __builtin_amdgcn_mfma_f32_32x32x16_bf16(alo, bh1, acc1, 0, 0, 0);
        acc0 = __builtin_amdgcn_mfma_f32_32x32x16_bf16(ahi, bl0, acc0, 0, 0, 0);
        acc1 = __builtin_amdgcn_mfma_f32_32x32x16_bf16(ahi, bl1, acc1, 0, 0, 0);
    }

    // ---- epilogue: h = relu(acc + b1); q = h . w2 + b2 ----
    const int cl = lane & 31;
    const float b1v0 = b1[a * HIDDEN + cl];
    const float b1v1 = b1[a * HIDDEN + 32 + cl];
    const float w2v0 = W2[a * HIDDEN + cl];
    const float w2v1 = W2[a * HIDDEN + 32 + cl];
    const float b2v  = b2[a];

    float v[16];
#pragma unroll
    for (int i = 0; i < 16; ++i) {
        float h0 = fmaxf(acc0[i] + b1v0, 0.f);
        float h1 = fmaxf(acc1[i] + b1v1, 0.f);
        v[i] = h0 * w2v0 + h1 * w2v1;
    }
    // reduce over the 32-lane column groups (xor offsets < 32 stay in-half)
#pragma unroll
    for (int off = 16; off >= 1; off >>= 1) {
#pragma unroll
        for (int i = 0; i < 16; ++i) v[i] += __shfl_xor(v[i], off, 64);
    }

    if (cl == 0) {
        const int r0 = blockIdx.x * MTILE + wv * 32;
#pragma unroll
        for (int i = 0; i < 16; ++i) {
            int row = (i & 3) + 8 * (i >> 2) + 4 * kg;  // verified C/D row map
            out[(size_t)(r0 + row) * NAGENTS + a] = v[i] + b2v;
        }
    }
}

extern "C" void kernel_launch(void* const* d_in, const int* in_sizes, int n_in,
                              void* d_out, int out_size, void* d_ws, size_t ws_size,
                              hipStream_t stream) {
    const float* obs  = (const float*)d_in[0];
    const float* msgs = (const float*)d_in[1];
    const float* W1   = (const float*)d_in[2];
    const float* b1   = (const float*)d_in[3];
    const float* W2   = (const float*)d_in[4];
    const float* b2   = (const float*)d_in[5];
    float* out = (float*)d_out;

    dim3 grid(ROWS / MTILE, NAGENTS);   // (64, 8); x-major dispatch keeps
                                        // same-m different-agent blocks near
                                        // each other for msgs L2 sharing
    accritic_mfma_kernel<<<grid, dim3(512), 0, stream>>>(obs, msgs, W1, b1, W2, b2, out);
}

// Round 5
// 121.561 us; speedup vs baseline: 1.0279x; 1.0279x over previous
//
#include <hip/hip_runtime.h>

// ACCriticNSMsg — bf16 hi/lo split MFMA, MLP fix (resubmit; R4 bench never ran).
// bs=64, T=256, n=8, msg=16, obs=128, hidden=64, in_dim=240. out (bs,T,n,1) f32.
//
// R3 measured: 42.5us, MfmaUtil 10%, VALUBusy 20%, HBM 12% -> latency-bound.
// VGPR=52: compiler kept ~2 loads in flight; 15 K-steps serialized on ~300cy
// scattered-load latency. Fix: preload ALL 30 X float4 into registers first
// (30-deep MLP per thread), launch_bounds(512,2) to allow ~200 VGPR.
// Also: truncate-hi split (hi = top 16 bits, residual exact, lo = RNE(resid))
// cuts conversion VALU ~40% vs double-RNE. Missing term lo*Wlo ~ 2^-16 rel.

#define NAGENTS 8
#define MSG_LEN 16
#define OBS_DIM 128
#define HIDDEN  64
#define IN_DIM  240
#define TT      256
#define ROWS    16384
#define KSTEPS  15
#define MTILE   256
#define NFRAG   (KSTEPS * 2 * 64 * 8)   // 15360 = one full W1_a in fragments

typedef __attribute__((ext_vector_type(8)))  short bf16x8;
typedef __attribute__((ext_vector_type(16))) float f32x16;

__device__ __forceinline__ unsigned short f2bf_rne(float x) {
    unsigned u = __float_as_uint(x);
    u += 0x7fffu + ((u >> 16) & 1u);
    return (unsigned short)(u >> 16);
}

__global__ __launch_bounds__(512, 2) void accritic_mfma_kernel(
    const float* __restrict__ obs,   // (bs,T,n,128)
    const float* __restrict__ msgs,  // (bs,T,n,16)
    const float* __restrict__ W1,    // (n,240,64)
    const float* __restrict__ b1,    // (n,64)
    const float* __restrict__ W2,    // (n,64,1)
    const float* __restrict__ b2,    // (n,1)
    float* __restrict__ out)         // (bs,T,n,1)
{
    __shared__ unsigned short WH[NFRAG];
    __shared__ unsigned short WL[NFRAG];

    const int a   = blockIdx.y;
    const int tid = threadIdx.x;
    const float* __restrict__ w1a = W1 + (size_t)a * IN_DIM * HIDDEN;

    // ---- stage W1_a as hi/lo bf16 fragments (30 loads issued, then convert) ----
    // entry e = ((ks*2 + nt)*64 + lane)*8 + j  ->  k = ks*16 + (lane>>5)*8 + j,
    //                                              col = nt*32 + (lane&31)
    {
        float wreg[NFRAG / 512];
#pragma unroll
        for (int i = 0; i < NFRAG / 512; ++i) {
            int e    = tid + i * 512;
            int j    = e & 7;
            int lane = (e >> 3) & 63;
            int nt   = (e >> 9) & 1;
            int ks   = e >> 10;
            int k    = ks * 16 + (lane >> 5) * 8 + j;
            int col  = nt * 32 + (lane & 31);
            wreg[i]  = w1a[k * HIDDEN + col];
        }
#pragma unroll
        for (int i = 0; i < NFRAG / 512; ++i) {
            int e = tid + i * 512;
            unsigned u = __float_as_uint(wreg[i]);
            float hif  = __uint_as_float(u & 0xffff0000u);
            WH[e] = (unsigned short)(u >> 16);
            WL[e] = f2bf_rne(wreg[i] - hif);
        }
    }
    __syncthreads();

    const int wv   = tid >> 6;
    const int lane = tid & 63;
    const int rl   = lane & 31;      // A row within the wave's 32-row slab
    const int kg   = lane >> 5;      // k-group (8 elems each)
    const int r    = blockIdx.x * MTILE + wv * 32 + rl;   // global row = b*T + t
    const int t    = r & (TT - 1);
    const bool zmsg = (t == 0);
    const int  rs   = zmsg ? r : r - 1;

    // ---- preload ALL X data: 16 obs float4 + 14 msg float4 (30-deep MLP) ----
    const float4* __restrict__ ob4 =
        reinterpret_cast<const float4*>(obs + ((size_t)r * NAGENTS + a) * OBS_DIM + kg * 8);
    const float4* __restrict__ mg4 =
        reinterpret_cast<const float4*>(msgs + (size_t)rs * NAGENTS * MSG_LEN + kg * 8);

    float4 ox[16];
#pragma unroll
    for (int ks = 0; ks < 8; ++ks) {
        ox[2 * ks]     = ob4[ks * 4];
        ox[2 * ks + 1] = ob4[ks * 4 + 1];
    }
    float4 mx[14];
#pragma unroll
    for (int p = 0; p < 7; ++p) {
        int jsrc = (p < a) ? p : p + 1;          // ascending j != a
        mx[2 * p]     = mg4[jsrc * 4];
        mx[2 * p + 1] = mg4[jsrc * 4 + 1];
    }
    if (zmsg) {
#pragma unroll
        for (int i = 0; i < 14; ++i) mx[i] = make_float4(0.f, 0.f, 0.f, 0.f);
    }

    f32x16 acc0, acc1;
#pragma unroll
    for (int i = 0; i < 16; ++i) { acc0[i] = 0.f; acc1[i] = 0.f; }

    const bf16x8* __restrict__ WH8 = reinterpret_cast<const bf16x8*>(WH);
    const bf16x8* __restrict__ WL8 = reinterpret_cast<const bf16x8*>(WL);

#pragma unroll
    for (int ks = 0; ks < KSTEPS; ++ks) {
        float4 f0, f1;
        if (ks < 8) { f0 = ox[2 * ks];       f1 = ox[2 * ks + 1]; }
        else        { f0 = mx[2 * (ks - 8)]; f1 = mx[2 * (ks - 8) + 1]; }

        float xf[8] = { f0.x, f0.y, f0.z, f0.w, f1.x, f1.y, f1.z, f1.w };
        bf16x8 ahi, alo;
#pragma unroll
        for (int q = 0; q < 8; ++q) {
            unsigned u = __float_as_uint(xf[q]);
            float hif  = __uint_as_float(u & 0xffff0000u);
            ahi[q] = (short)(u >> 16);                 // truncate-hi (resid exact)
            alo[q] = (short)f2bf_rne(xf[q] - hif);     // RNE lo
        }

        bf16x8 bh0 = WH8[(ks * 2 + 0) * 64 + lane];
        bf16x8 bh1 = WH8[(ks * 2 + 1) * 64 + lane];
        bf16x8 bl0 = WL8[(ks * 2 + 0) * 64 + lane];
        bf16x8 bl1 = WL8[(ks * 2 + 1) * 64 + lane];

        acc0 = __builtin_amdgcn_mfma_f32_32x32x16_bf16(ahi, bh0, acc0, 0, 0, 0);
        acc1 = __builtin_amdgcn_mfma_f32_32x32x16_bf16(ahi, bh1, acc1, 0, 0, 0);
        acc0 = __builtin_amdgcn_mfma_f32_32x32x16_bf16(alo, bh0, acc0, 0, 0, 0);
        acc1 = __builtin_amdgcn_mfma_f32_32x32x16_bf16(alo, bh1, acc1, 0, 0, 0);
        acc0 = __builtin_amdgcn_mfma_f32_32x32x16_bf16(ahi, bl0, acc0, 0, 0, 0);
        acc1 = __builtin_amdgcn_mfma_f32_32x32x16_bf16(ahi, bl1, acc1, 0, 0, 0);
    }

    // ---- epilogue: h = relu(acc + b1); q = h . w2 + b2 ----
    const int cl = lane & 31;
    const float b1v0 = b1[a * HIDDEN + cl];
    const float b1v1 = b1[a * HIDDEN + 32 + cl];
    const float w2v0 = W2[a * HIDDEN + cl];
    const float w2v1 = W2[a * HIDDEN + 32 + cl];
    const float b2v  = b2[a];

    float v[16];
#pragma unroll
    for (int i = 0; i < 16; ++i) {
        float h0 = fmaxf(acc0[i] + b1v0, 0.f);
        float h1 = fmaxf(acc1[i] + b1v1, 0.f);
        v[i] = h0 * w2v0 + h1 * w2v1;
    }
#pragma unroll
    for (int off = 16; off >= 1; off >>= 1) {
#pragma unroll
        for (int i = 0; i < 16; ++i) v[i] += __shfl_xor(v[i], off, 64);
    }

    if (cl == 0) {
        const int r0 = blockIdx.x * MTILE + wv * 32;
#pragma unroll
        for (int i = 0; i < 16; ++i) {
            int row = (i & 3) + 8 * (i >> 2) + 4 * kg;  // HW-verified C/D row map
            out[(size_t)(r0 + row) * NAGENTS + a] = v[i] + b2v;
        }
    }
}

extern "C" void kernel_launch(void* const* d_in, const int* in_sizes, int n_in,
                              void* d_out, int out_size, void* d_ws, size_t ws_size,
                              hipStream_t stream) {
    const float* obs  = (const float*)d_in[0];
    const float* msgs = (const float*)d_in[1];
    const float* W1   = (const float*)d_in[2];
    const float* b1   = (const float*)d_in[3];
    const float* W2   = (const float*)d_in[4];
    const float* b2   = (const float*)d_in[5];
    float* out = (float*)d_out;

    dim3 grid(ROWS / MTILE, NAGENTS);
    accritic_mfma_kernel<<<grid, dim3(512), 0, stream>>>(obs, msgs, W1, b1, W2, b2, out);
}